// Round 1
// baseline (2530.297 us; speedup 1.0000x reference)
//
#include <hip/hip_runtime.h>
#include <math.h>

#define BATCH 16
#define KCLS  19
#define CCH   512
#define HW    16384

#define SC    512     // hw sub-chunk staged in LDS
#define CHUNK 8192    // hw per block (2 chunks cover HW)
#define CTILE 32      // channels per block = 8 waves x 4

// ---------------- Kernel A: per-(b,k) softmax stats (max, 1/sum) ----------------
__global__ __launch_bounds__(256) void softmax_stats_kernel(
    const float* __restrict__ probs, float* __restrict__ stats) {
  const int bk = blockIdx.x;                      // 0..303
  const float4* row = (const float4*)(probs + (size_t)bk * HW);
  const int tid  = threadIdx.x;
  const int lane = tid & 63;
  const int wave = tid >> 6;
  __shared__ float red[4];

  // pass 1: max
  float m = -1e30f;
  for (int i = tid; i < HW / 4; i += 256) {
    float4 v = row[i];
    m = fmaxf(m, fmaxf(fmaxf(v.x, v.y), fmaxf(v.z, v.w)));
  }
  for (int off = 32; off > 0; off >>= 1) m = fmaxf(m, __shfl_xor(m, off));
  if (lane == 0) red[wave] = m;
  __syncthreads();
  m = fmaxf(fmaxf(red[0], red[1]), fmaxf(red[2], red[3]));

  // pass 2: sum of exp (row is L2-hot)
  float s = 0.f;
  for (int i = tid; i < HW / 4; i += 256) {
    float4 v = row[i];
    s += __expf(v.x - m) + __expf(v.y - m) + __expf(v.z - m) + __expf(v.w - m);
  }
  for (int off = 32; off > 0; off >>= 1) s += __shfl_xor(s, off);
  __syncthreads();                 // everyone done reading red[] (max phase)
  if (lane == 0) red[wave] = s;
  __syncthreads();
  if (tid == 0) {
    float total = red[0] + red[1] + red[2] + red[3];
    stats[2 * bk]     = m;
    stats[2 * bk + 1] = 1.0f / total;
  }
}

// ---------------- Kernel B: ctx[b,k,c] = sum_hw attn * feat ----------------
// grid = 512 blocks: bid = b(4b) | ctile(4b) | chunk(1b). b = bid&15 keeps each
// batch's 32 blocks on one XCD (bid%8 dispatch) -> probs re-reads hit that L2.
__global__ __launch_bounds__(512, 4) void gather_kernel(
    const float* __restrict__ feat, const float* __restrict__ probs,
    const float* __restrict__ stats, float* __restrict__ out) {
  __shared__ float attn[KCLS][SC];   // 38 KB
  __shared__ float sm[KCLS], si[KCLS];

  const int bid   = blockIdx.x;
  const int b     = bid & 15;
  const int rest  = bid >> 4;
  const int ctile = rest & 15;       // 16 tiles of 32 channels
  const int chunk = rest >> 4;       // 0..1
  const int hw0   = chunk * CHUNK;

  const int tid  = threadIdx.x;
  const int wave = tid >> 6;         // 8 waves
  const int lane = tid & 63;
  const int c0   = ctile * CTILE + wave * 4;   // this wave's 4 channels

  if (tid < KCLS) {
    sm[tid] = stats[2 * (b * KCLS + tid)];
    si[tid] = stats[2 * (b * KCLS + tid) + 1];
  }

  const float* fp = feat + ((size_t)(b * CCH + c0)) * HW + hw0;
  const float* pb = probs + (size_t)b * KCLS * HW + hw0;

  float acc[KCLS][4];
  #pragma unroll
  for (int k = 0; k < KCLS; k++)
    #pragma unroll
    for (int j = 0; j < 4; j++) acc[k][j] = 0.f;

  for (int s = 0; s < CHUNK; s += SC) {
    __syncthreads();   // previous GEMM done with attn[] (also covers sm/si init)
    // ---- stage attn for this sub-chunk: exp computed once per block ----
    for (int idx = tid; idx < KCLS * (SC / 4); idx += 512) {
      int k  = idx / (SC / 4);
      int hv = idx - k * (SC / 4);
      float4 p = *(const float4*)(pb + (size_t)k * HW + s + hv * 4);
      float m = sm[k], iv = si[k];
      float4 a;
      a.x = __expf(p.x - m) * iv;
      a.y = __expf(p.y - m) * iv;
      a.z = __expf(p.z - m) * iv;
      a.w = __expf(p.w - m) * iv;
      *(float4*)&attn[k][hv * 4] = a;
    }
    __syncthreads();
    // ---- GEMM phase: each lane does 4 consecutive hw, 4 channels, 19 k ----
    #pragma unroll
    for (int it = 0; it < SC; it += 256) {
      const int hw = it + lane * 4;
      float4 f0 = *(const float4*)(fp + (size_t)0 * HW + s + hw);
      float4 f1 = *(const float4*)(fp + (size_t)1 * HW + s + hw);
      float4 f2 = *(const float4*)(fp + (size_t)2 * HW + s + hw);
      float4 f3 = *(const float4*)(fp + (size_t)3 * HW + s + hw);
      #pragma unroll
      for (int k = 0; k < KCLS; k++) {
        float4 a = *(const float4*)&attn[k][hw];
        acc[k][0] += a.x * f0.x + a.y * f0.y + a.z * f0.z + a.w * f0.w;
        acc[k][1] += a.x * f1.x + a.y * f1.y + a.z * f1.z + a.w * f1.w;
        acc[k][2] += a.x * f2.x + a.y * f2.y + a.z * f2.z + a.w * f2.w;
        acc[k][3] += a.x * f3.x + a.y * f3.y + a.z * f3.z + a.w * f3.w;
      }
    }
  }

  // ---- cross-lane (hw) reduce within wave; one lane per k writes 4 atomics ----
  #pragma unroll
  for (int k = 0; k < KCLS; k++) {
    #pragma unroll
    for (int j = 0; j < 4; j++) {
      float v = acc[k][j];
      for (int off = 32; off > 0; off >>= 1) v += __shfl_xor(v, off);
      acc[k][j] = v;
    }
  }
  #pragma unroll
  for (int k = 0; k < KCLS; k++) {
    if (lane == k) {
      #pragma unroll
      for (int j = 0; j < 4; j++)
        atomicAdd(out + (size_t)(b * CCH + c0 + j) * KCLS + k, acc[k][j]);
    }
  }
}

extern "C" void kernel_launch(void* const* d_in, const int* in_sizes, int n_in,
                              void* d_out, int out_size, void* d_ws, size_t ws_size,
                              hipStream_t stream) {
  const float* feat  = (const float*)d_in[0];   // [16, 512, 128, 128] f32
  const float* probs = (const float*)d_in[1];   // [16, 19, 128, 128] f32
  float* out   = (float*)d_out;                 // [16, 512, 19, 1] f32
  float* stats = (float*)d_ws;                  // 304 * 2 floats

  // atomics accumulate into out -> must start at zero every call
  hipMemsetAsync(d_out, 0, (size_t)out_size * sizeof(float), stream);

  softmax_stats_kernel<<<BATCH * KCLS, 256, 0, stream>>>(probs, stats);
  gather_kernel<<<512, 512, 0, stream>>>(feat, probs, stats, out);
}

// Round 2
// 1036.993 us; speedup vs baseline: 2.4400x; 2.4400x over previous
//
#include <hip/hip_runtime.h>
#include <math.h>

#define BATCH 16
#define KCLS  19
#define CCH   512
#define HW    16384

#define SC    512     // hw sub-chunk staged in LDS
#define CHUNK 8192    // hw per block (2 chunks cover HW)
#define CTILE 32      // channels per block = 8 waves x 4

// ---------------- Kernel A: per-(b,k) softmax stats (max, 1/sum) ----------------
__global__ __launch_bounds__(256) void softmax_stats_kernel(
    const float* __restrict__ probs, float* __restrict__ stats) {
  const int bk = blockIdx.x;                      // 0..303
  const float4* row = (const float4*)(probs + (size_t)bk * HW);
  const int tid  = threadIdx.x;
  const int lane = tid & 63;
  const int wave = tid >> 6;
  __shared__ float red[4];

  // pass 1: max
  float m = -1e30f;
  for (int i = tid; i < HW / 4; i += 256) {
    float4 v = row[i];
    m = fmaxf(m, fmaxf(fmaxf(v.x, v.y), fmaxf(v.z, v.w)));
  }
  for (int off = 32; off > 0; off >>= 1) m = fmaxf(m, __shfl_xor(m, off));
  if (lane == 0) red[wave] = m;
  __syncthreads();
  m = fmaxf(fmaxf(red[0], red[1]), fmaxf(red[2], red[3]));

  // pass 2: sum of exp (row is L2-hot)
  float s = 0.f;
  for (int i = tid; i < HW / 4; i += 256) {
    float4 v = row[i];
    s += __expf(v.x - m) + __expf(v.y - m) + __expf(v.z - m) + __expf(v.w - m);
  }
  for (int off = 32; off > 0; off >>= 1) s += __shfl_xor(s, off);
  __syncthreads();                 // everyone done reading red[] (max phase)
  if (lane == 0) red[wave] = s;
  __syncthreads();
  if (tid == 0) {
    float total = red[0] + red[1] + red[2] + red[3];
    stats[2 * bk]     = m;
    stats[2 * bk + 1] = 1.0f / total;
  }
}

// ---------------- Kernel B: ctx[b,k,c] = sum_hw attn * feat ----------------
// grid = 512 blocks: bid = b(4b) | ctile(4b) | chunk(1b). b = bid&15 keeps each
// batch's 32 blocks on one XCD (bid%8 dispatch) -> probs re-reads hit that L2.
// launch_bounds(512, 2): VGPR budget >=128 so acc[19][4] (~114 live VGPRs)
// stays in registers. (512,4) throttled to 64 VGPR -> 5 GB of scratch spill.
__global__ __launch_bounds__(512, 2) void gather_kernel(
    const float* __restrict__ feat, const float* __restrict__ probs,
    const float* __restrict__ stats, float* __restrict__ out) {
  __shared__ float attn[KCLS][SC];   // 38 KB
  __shared__ float sm[KCLS], si[KCLS];

  const int bid   = blockIdx.x;
  const int b     = bid & 15;
  const int rest  = bid >> 4;
  const int ctile = rest & 15;       // 16 tiles of 32 channels
  const int chunk = rest >> 4;       // 0..1
  const int hw0   = chunk * CHUNK;

  const int tid  = threadIdx.x;
  const int wave = tid >> 6;         // 8 waves
  const int lane = tid & 63;
  const int c0   = ctile * CTILE + wave * 4;   // this wave's 4 channels

  if (tid < KCLS) {
    sm[tid] = stats[2 * (b * KCLS + tid)];
    si[tid] = stats[2 * (b * KCLS + tid) + 1];
  }

  const float* fp = feat + ((size_t)(b * CCH + c0)) * HW + hw0;
  const float* pb = probs + (size_t)b * KCLS * HW + hw0;

  float acc[KCLS][4];
  #pragma unroll
  for (int k = 0; k < KCLS; k++)
    #pragma unroll
    for (int j = 0; j < 4; j++) acc[k][j] = 0.f;

  for (int s = 0; s < CHUNK; s += SC) {
    __syncthreads();   // previous GEMM done with attn[] (also covers sm/si init)
    // ---- stage attn for this sub-chunk: exp computed once per block ----
    for (int idx = tid; idx < KCLS * (SC / 4); idx += 512) {
      int k  = idx / (SC / 4);
      int hv = idx - k * (SC / 4);
      float4 p = *(const float4*)(pb + (size_t)k * HW + s + hv * 4);
      float m = sm[k], iv = si[k];
      float4 a;
      a.x = __expf(p.x - m) * iv;
      a.y = __expf(p.y - m) * iv;
      a.z = __expf(p.z - m) * iv;
      a.w = __expf(p.w - m) * iv;
      *(float4*)&attn[k][hv * 4] = a;
    }
    __syncthreads();
    // ---- GEMM phase: each lane does 4 consecutive hw, 4 channels, 19 k ----
    #pragma unroll
    for (int it = 0; it < SC; it += 256) {
      const int hw = it + lane * 4;
      float4 f0 = *(const float4*)(fp + (size_t)0 * HW + s + hw);
      float4 f1 = *(const float4*)(fp + (size_t)1 * HW + s + hw);
      float4 f2 = *(const float4*)(fp + (size_t)2 * HW + s + hw);
      float4 f3 = *(const float4*)(fp + (size_t)3 * HW + s + hw);
      #pragma unroll
      for (int k = 0; k < KCLS; k++) {
        float4 a = *(const float4*)&attn[k][hw];
        acc[k][0] += a.x * f0.x + a.y * f0.y + a.z * f0.z + a.w * f0.w;
        acc[k][1] += a.x * f1.x + a.y * f1.y + a.z * f1.z + a.w * f1.w;
        acc[k][2] += a.x * f2.x + a.y * f2.y + a.z * f2.z + a.w * f2.w;
        acc[k][3] += a.x * f3.x + a.y * f3.y + a.z * f3.z + a.w * f3.w;
      }
    }
  }

  // ---- cross-lane (hw) reduce within wave; one lane per k writes 4 atomics ----
  #pragma unroll
  for (int k = 0; k < KCLS; k++) {
    #pragma unroll
    for (int j = 0; j < 4; j++) {
      float v = acc[k][j];
      for (int off = 32; off > 0; off >>= 1) v += __shfl_xor(v, off);
      acc[k][j] = v;
    }
  }
  #pragma unroll
  for (int k = 0; k < KCLS; k++) {
    if (lane == k) {
      #pragma unroll
      for (int j = 0; j < 4; j++)
        atomicAdd(out + (size_t)(b * CCH + c0 + j) * KCLS + k, acc[k][j]);
    }
  }
}

extern "C" void kernel_launch(void* const* d_in, const int* in_sizes, int n_in,
                              void* d_out, int out_size, void* d_ws, size_t ws_size,
                              hipStream_t stream) {
  const float* feat  = (const float*)d_in[0];   // [16, 512, 128, 128] f32
  const float* probs = (const float*)d_in[1];   // [16, 19, 128, 128] f32
  float* out   = (float*)d_out;                 // [16, 512, 19, 1] f32
  float* stats = (float*)d_ws;                  // 304 * 2 floats

  // atomics accumulate into out -> must start at zero every call
  hipMemsetAsync(d_out, 0, (size_t)out_size * sizeof(float), stream);

  softmax_stats_kernel<<<BATCH * KCLS, 256, 0, stream>>>(probs, stats);
  gather_kernel<<<512, 512, 0, stream>>>(feat, probs, stats, out);
}

// Round 3
// 406.452 us; speedup vs baseline: 6.2253x; 2.5513x over previous
//
#include <hip/hip_runtime.h>
#include <math.h>

#define BATCH 16
#define KCLS  19
#define CCH   512
#define HW    16384

#define SC    512     // hw sub-chunk staged in LDS
#define CHUNK 8192    // hw per block (2 chunks cover HW)
#define CTILE 16      // channels per block = 4 waves x 4

// ---------------- Kernel A: per-(b,k) softmax stats (max, 1/sum) ----------------
__global__ __launch_bounds__(256) void softmax_stats_kernel(
    const float* __restrict__ probs, float* __restrict__ stats) {
  const int bk = blockIdx.x;                      // 0..303
  const float4* row = (const float4*)(probs + (size_t)bk * HW);
  const int tid  = threadIdx.x;
  const int lane = tid & 63;
  const int wave = tid >> 6;
  __shared__ float red[4];

  // pass 1: max
  float m = -1e30f;
  for (int i = tid; i < HW / 4; i += 256) {
    float4 v = row[i];
    m = fmaxf(m, fmaxf(fmaxf(v.x, v.y), fmaxf(v.z, v.w)));
  }
  for (int off = 32; off > 0; off >>= 1) m = fmaxf(m, __shfl_xor(m, off));
  if (lane == 0) red[wave] = m;
  __syncthreads();
  m = fmaxf(fmaxf(red[0], red[1]), fmaxf(red[2], red[3]));

  // pass 2: sum of exp (row is L2-hot)
  float s = 0.f;
  for (int i = tid; i < HW / 4; i += 256) {
    float4 v = row[i];
    s += __expf(v.x - m) + __expf(v.y - m) + __expf(v.z - m) + __expf(v.w - m);
  }
  for (int off = 32; off > 0; off >>= 1) s += __shfl_xor(s, off);
  __syncthreads();                 // everyone done reading red[] (max phase)
  if (lane == 0) red[wave] = s;
  __syncthreads();
  if (tid == 0) {
    float total = red[0] + red[1] + red[2] + red[3];
    stats[2 * bk]     = m;
    stats[2 * bk + 1] = 1.0f / total;
  }
}

// ---------------- Kernel B: ctx[b,k,c] = sum_hw attn * feat ----------------
// grid = 1024 blocks of 256 threads: bid = b(4b) | ctile(5b) | chunk(1b).
// b = bid&15 -> bid%8 = b%8, so each batch's blocks land on one XCD and its
// 1.24 MB probs slice stays L2-resident across re-reads.
// NO min-waves launch bound: the inner loop's live set (76 acc + feat +
// hoisted attn reads) needs ~170 VGPR; capping at 128 spilled 2 GB to scratch.
__global__ __launch_bounds__(256) void gather_kernel(
    const float* __restrict__ feat, const float* __restrict__ probs,
    const float* __restrict__ stats, float* __restrict__ out) {
  __shared__ float attn[KCLS][SC];   // 38 KB
  __shared__ float sm[KCLS], si[KCLS];

  const int bid   = blockIdx.x;
  const int b     = bid & 15;
  const int rest  = bid >> 4;
  const int ctile = rest & 31;       // 32 tiles of 16 channels
  const int chunk = rest >> 5;       // 0..1
  const int hw0   = chunk * CHUNK;

  const int tid  = threadIdx.x;
  const int wave = tid >> 6;         // 4 waves
  const int lane = tid & 63;
  const int c0   = ctile * CTILE + wave * 4;   // this wave's 4 channels

  if (tid < KCLS) {
    sm[tid] = stats[2 * (b * KCLS + tid)];
    si[tid] = stats[2 * (b * KCLS + tid) + 1];
  }

  const float* fp = feat + ((size_t)(b * CCH + c0)) * HW + hw0;
  const float* pb = probs + (size_t)b * KCLS * HW + hw0;

  float acc[KCLS][4];
  #pragma unroll
  for (int k = 0; k < KCLS; k++)
    #pragma unroll
    for (int j = 0; j < 4; j++) acc[k][j] = 0.f;

  for (int s = 0; s < CHUNK; s += SC) {
    __syncthreads();   // previous GEMM done with attn[] (also covers sm/si init)
    // ---- stage attn for this sub-chunk: exp computed once per block ----
    // KCLS*(SC/4) = 19*128 = 2432 float4 items; k = idx>>7, hv = idx&127
    for (int idx = tid; idx < KCLS * (SC / 4); idx += 256) {
      int k  = idx >> 7;
      int hv = idx & 127;
      float4 p = *(const float4*)(pb + (size_t)k * HW + s + hv * 4);
      float m = sm[k], iv = si[k];
      float4 a;
      a.x = __expf(p.x - m) * iv;
      a.y = __expf(p.y - m) * iv;
      a.z = __expf(p.z - m) * iv;
      a.w = __expf(p.w - m) * iv;
      *(float4*)&attn[k][hv * 4] = a;
    }
    __syncthreads();
    // ---- GEMM phase: each lane does 4 consecutive hw, 4 channels, 19 k ----
    #pragma unroll
    for (int it = 0; it < SC; it += 256) {
      const int hw = it + lane * 4;
      float4 f0 = *(const float4*)(fp + (size_t)0 * HW + s + hw);
      float4 f1 = *(const float4*)(fp + (size_t)1 * HW + s + hw);
      float4 f2 = *(const float4*)(fp + (size_t)2 * HW + s + hw);
      float4 f3 = *(const float4*)(fp + (size_t)3 * HW + s + hw);
      #pragma unroll
      for (int k = 0; k < KCLS; k++) {
        float4 a = *(const float4*)&attn[k][hw];
        acc[k][0] += a.x * f0.x + a.y * f0.y + a.z * f0.z + a.w * f0.w;
        acc[k][1] += a.x * f1.x + a.y * f1.y + a.z * f1.z + a.w * f1.w;
        acc[k][2] += a.x * f2.x + a.y * f2.y + a.z * f2.z + a.w * f2.w;
        acc[k][3] += a.x * f3.x + a.y * f3.y + a.z * f3.z + a.w * f3.w;
      }
    }
  }

  // ---- cross-lane (hw) reduce within wave; one lane per k writes 4 atomics ----
  #pragma unroll
  for (int k = 0; k < KCLS; k++) {
    #pragma unroll
    for (int j = 0; j < 4; j++) {
      float v = acc[k][j];
      for (int off = 32; off > 0; off >>= 1) v += __shfl_xor(v, off);
      acc[k][j] = v;
    }
  }
  #pragma unroll
  for (int k = 0; k < KCLS; k++) {
    if (lane == k) {
      #pragma unroll
      for (int j = 0; j < 4; j++)
        atomicAdd(out + (size_t)(b * CCH + c0 + j) * KCLS + k, acc[k][j]);
    }
  }
}

extern "C" void kernel_launch(void* const* d_in, const int* in_sizes, int n_in,
                              void* d_out, int out_size, void* d_ws, size_t ws_size,
                              hipStream_t stream) {
  const float* feat  = (const float*)d_in[0];   // [16, 512, 128, 128] f32
  const float* probs = (const float*)d_in[1];   // [16, 19, 128, 128] f32
  float* out   = (float*)d_out;                 // [16, 512, 19, 1] f32
  float* stats = (float*)d_ws;                  // 304 * 2 floats

  // atomics accumulate into out -> must start at zero every call
  hipMemsetAsync(d_out, 0, (size_t)out_size * sizeof(float), stream);

  softmax_stats_kernel<<<BATCH * KCLS, 256, 0, stream>>>(probs, stats);
  gather_kernel<<<16 * 32 * 2, 256, 0, stream>>>(feat, probs, stats, out);
}